// Round 3
// baseline (928.167 us; speedup 1.0000x reference)
//
#include <hip/hip_runtime.h>
#include <math.h>

typedef __attribute__((ext_vector_type(8))) short bf8;
typedef __attribute__((ext_vector_type(4))) short s4;
typedef __attribute__((ext_vector_type(4))) float f4;

__device__ __forceinline__ float bf2f(short s) {
    union { unsigned u; float f; } v; v.u = ((unsigned)(unsigned short)s) << 16; return v.f;
}
__device__ __forceinline__ short f2bf(float f) {
    union { float f; unsigned u; } v; v.f = f;
    unsigned r = (v.u + 0x7FFFu + ((v.u >> 16) & 1u)) >> 16;
    return (short)r;
}

// ---------------------------------------------------------------------------
// Positional embedding: pos[512][768] bf16 (row 511 zero pad).
// fp64 to avoid fp32 lgamma cancellation at concentration up to 65536.
// ---------------------------------------------------------------------------
__global__ void pos_kernel(short* __restrict__ P) {
    const int row = blockIdx.x;      // 0..511
    const int j = threadIdx.x;       // 0..127  (nb = 128)
    if (row == 511) {
        for (int t = j; t < 768; t += 128) P[511 * 768 + t] = 0;
        return;
    }
    const double dist = (double)(row - 255);
    const double ad = fabs(dist);
    // exponential basis: half_life = 2^(3 + 5*j/127)
    double hl = exp2(3.0 + 5.0 * (double)j / 127.0);
    double fe = exp(-M_LN2 / hl * ad);
    // central-mask basis: 2^(j+1)-1 > |d|
    double cw = exp2((double)(j + 1)) - 1.0;
    double fc = (cw > ad) ? 1.0 : 0.0;
    // gamma basis: stddev=1, mean = 2+2j, conc=mean^2, rate=mean
    double m = 2.0 + 2.0 * (double)j;
    double conc = m * m;
    double lun = (ad == 0.0) ? -INFINITY : (conc - 1.0) * log(ad);
    lun -= m * ad;
    double lnorm = lgamma(conc) - conc * log(m);
    double prob = exp(lun - lnorm) + 1e-8;
    __shared__ double red[128];
    red[j] = prob;
    __syncthreads();
    for (int s2 = 64; s2 > 0; s2 >>= 1) {
        if (j < s2) red[j] = fmax(red[j], red[j + s2]);
        __syncthreads();
    }
    double fg = prob / red[0];
    float sg = (dist > 0.0) ? 1.f : ((dist < 0.0) ? -1.f : 0.f);
    int base = row * 768;
    P[base + j]        = f2bf((float)fe);
    P[base + 128 + j]  = f2bf((float)fc);
    P[base + 256 + j]  = f2bf((float)fg);
    P[base + 384 + j]  = f2bf(sg * (float)fe);
    P[base + 512 + j]  = f2bf(sg * (float)fc);
    P[base + 640 + j]  = f2bf(sg * (float)fg);
}

// ---------------------------------------------------------------------------
// Generic MFMA GEMM: C(MxN) = A(MxK) @ B(KxN), bf16 MFMA, fp32 accum.
// 128x128 block tile, 4 waves (2x2 of 64x64), BK=32. B is always fp32.
// mode 0: A bf16 row-major;           C -> bf16 store (Cb)
// mode 1: A fp32 row-major;           C -> qkv de-interleave scatter (bf16)
// mode 2: A bf16 gather from (b,h,n,d); C -> fp32 + fp32 bias (Cf)
// ---------------------------------------------------------------------------
__global__ __launch_bounds__(256) void gemm_k(
    const void* __restrict__ Ap, const float* __restrict__ B,
    int M, int N, int K, int mode,
    short* __restrict__ Cb, float* __restrict__ Cf, const float* __restrict__ bias,
    short* __restrict__ Qo, short* __restrict__ Ko, short* __restrict__ Vo)
{
    __shared__ __attribute__((aligned(16))) short As[128 * 48];
    __shared__ __attribute__((aligned(16))) short Bs[128 * 48];
    const int tid = threadIdx.x;
    const int lane = tid & 63;
    const int wave = tid >> 6;
    const int wm = wave >> 1, wn = wave & 1;
    const int c = lane & 15, quad = lane >> 4;
    const int m0 = blockIdx.x * 128, n0 = blockIdx.y * 128;
    const short* Ab = (const short*)Ap;
    const float* Af = (const float*)Ap;

    f4 acc[4][4];
#pragma unroll
    for (int i = 0; i < 4; ++i)
#pragma unroll
        for (int jx = 0; jx < 4; ++jx) acc[i][jx] = (f4){0.f, 0.f, 0.f, 0.f};

    for (int k0 = 0; k0 < K; k0 += 32) {
        // ---- stage A (128x32 -> As[row][k], bf16) ----
        if (mode == 1) {
#pragma unroll
            for (int i = 0; i < 4; ++i) {
                int idx = tid + i * 256;               // 1024 float4 chunks
                int row = idx >> 3, ch = (idx & 7) << 2;
                float4 v = *(const float4*)(Af + (long)(m0 + row) * K + k0 + ch);
                s4 s; s.x = f2bf(v.x); s.y = f2bf(v.y); s.z = f2bf(v.z); s.w = f2bf(v.w);
                *(s4*)(&As[row * 48 + ch]) = s;
            }
        } else if (mode == 2) {
#pragma unroll
            for (int i = 0; i < 2; ++i) {              // 512 bf8 chunks
                int idx = tid + i * 256;
                int row = idx >> 2, ch = (idx & 3) << 3;
                int m = m0 + row, kk = k0 + ch;
                long off = ((long)((m >> 13) * 12 + (kk >> 6)) * 8192 + (m & 8191)) * 64 + (kk & 63);
                *(bf8*)(&As[row * 48 + ch]) = *(const bf8*)(Ab + off);
            }
        } else {
#pragma unroll
            for (int i = 0; i < 2; ++i) {              // 512 bf8 chunks
                int idx = tid + i * 256;
                int row = idx >> 2, ch = (idx & 3) << 3;
                *(bf8*)(&As[row * 48 + ch]) = *(const bf8*)(Ab + (long)(m0 + row) * K + k0 + ch);
            }
        }
        // ---- stage B (32x128 fp32 -> Bs[n][k] transposed, bf16) ----
#pragma unroll
        for (int i = 0; i < 4; ++i) {
            int idx = tid + i * 256;                   // 1024 float4 chunks
            int row = idx >> 5, ch = (idx & 31) << 2;
            float4 v = *(const float4*)(B + (long)(k0 + row) * N + n0 + ch);
            Bs[(ch + 0) * 48 + row] = f2bf(v.x);
            Bs[(ch + 1) * 48 + row] = f2bf(v.y);
            Bs[(ch + 2) * 48 + row] = f2bf(v.z);
            Bs[(ch + 3) * 48 + row] = f2bf(v.w);
        }
        __syncthreads();
        bf8 a[4], b[4];
#pragma unroll
        for (int mt = 0; mt < 4; ++mt)
            a[mt] = *(const bf8*)(&As[(wm * 64 + mt * 16 + c) * 48 + quad * 8]);
#pragma unroll
        for (int nt = 0; nt < 4; ++nt)
            b[nt] = *(const bf8*)(&Bs[(wn * 64 + nt * 16 + c) * 48 + quad * 8]);
#pragma unroll
        for (int mt = 0; mt < 4; ++mt)
#pragma unroll
            for (int nt = 0; nt < 4; ++nt)
                acc[mt][nt] = __builtin_amdgcn_mfma_f32_16x16x32_bf16(a[mt], b[nt], acc[mt][nt], 0, 0, 0);
        __syncthreads();
    }
#pragma unroll
    for (int mt = 0; mt < 4; ++mt)
#pragma unroll
        for (int nt = 0; nt < 4; ++nt)
#pragma unroll
            for (int r = 0; r < 4; ++r) {
                int m = m0 + wm * 64 + mt * 16 + quad * 4 + r;
                int n = n0 + wn * 64 + nt * 16 + c;
                float val = acc[mt][nt][r];
                if (mode == 1) {
                    int sel = n % 3, hd = n / 3;        // col = (h*64+d)*3 + sel
                    int h = hd >> 6, d = hd & 63;
                    int bb = m >> 13, nn = m & 8191;
                    long off = ((long)((bb * 12 + h) * 8192 + nn)) * 64 + d;
                    short* dst = (sel == 0) ? Qo : (sel == 1) ? Ko : Vo;
                    dst[off] = f2bf(val);
                } else if (mode == 2) {
                    Cf[(long)m * N + n] = val + bias[n];
                } else {
                    Cb[(long)m * N + n] = f2bf(val);
                }
            }
}

// ---------------------------------------------------------------------------
// Fused windowed attention with relative-shift position logits.
// block = 128 threads = 2 waves, each wave owns a 16-row strip; 8 blocks/window.
// Output written IN PLACE over this wave's own q rows ((b,h,n,d) layout):
// each wave reads only its own 16 q-rows (into registers, before any store).
// LDS: 64*264 + 2*16*264 shorts = 50,688 B  (< 64 KiB)
// ---------------------------------------------------------------------------
__global__ __launch_bounds__(128) void attn_k(
    short* __restrict__ Q, const short* __restrict__ Kk, const short* __restrict__ V,
    const short* __restrict__ RK,   // (512, 768) bf16, row 511 zero; col = h*64+d
    const float* __restrict__ rcb, const float* __restrict__ rpb)
{
    __shared__ __attribute__((aligned(16))) short Vs[64 * 264];     // [d][j]
    __shared__ __attribute__((aligned(16))) short Ps[2][16 * 264];  // per-wave probs
    const int bid = blockIdx.x;
    const int s = bid & 7, w = (bid >> 3) & 31;
    const int rest = bid >> 8;
    const int h = rest % 12, b = rest / 12;
    const int tid = threadIdx.x, lane = tid & 63, wave = tid >> 6;
    const int c = lane & 15, quad = lane >> 4;
    const int i0w = s * 32 + wave * 16;

    const long base_bh = ((long)(b * 12 + h) * 8192 + (long)w * 256) * 64;
    short* Qh = Q + base_bh;
    const short* Kh = Kk + base_bh;
    const short* Vh = V + base_bh;

    // stage V transposed into LDS: Vs[d][j]
    for (int p = tid; p < 2048; p += 128) {
        int row = p >> 3, ch = (p & 7) << 3;
        bf8 v = *(const bf8*)(Vh + row * 64 + ch);
#pragma unroll
        for (int u = 0; u < 8; ++u) Vs[(ch + u) * 264 + row] = v[u];
    }

    // Q fragments with content / position biases added (bf16)
    bf8 qc[2], qp[2];
#pragma unroll
    for (int ks = 0; ks < 2; ++ks) {
        bf8 qraw = *(const bf8*)(Qh + (i0w + c) * 64 + ks * 32 + quad * 8);
        float4 cb0 = *(const float4*)(rcb + h * 64 + ks * 32 + quad * 8);
        float4 cb1 = *(const float4*)(rcb + h * 64 + ks * 32 + quad * 8 + 4);
        float4 pb0 = *(const float4*)(rpb + h * 64 + ks * 32 + quad * 8);
        float4 pb1 = *(const float4*)(rpb + h * 64 + ks * 32 + quad * 8 + 4);
        float cbv[8] = {cb0.x, cb0.y, cb0.z, cb0.w, cb1.x, cb1.y, cb1.z, cb1.w};
        float pbv[8] = {pb0.x, pb0.y, pb0.z, pb0.w, pb1.x, pb1.y, pb1.z, pb1.w};
#pragma unroll
        for (int u = 0; u < 8; ++u) {
            float qv = bf2f(qraw[u]);
            qc[ks][u] = f2bf(qv + cbv[u]);
            qp[ks][u] = f2bf(qv + pbv[u]);
        }
    }
    __syncthreads();   // Vs ready

    // content scores S[16 tiles][4]: (Q+rcb) @ K^T  (16 x 256)
    f4 S[16];
#pragma unroll
    for (int ct = 0; ct < 16; ++ct) S[ct] = (f4){0.f, 0.f, 0.f, 0.f};
#pragma unroll
    for (int ct = 0; ct < 16; ++ct)
#pragma unroll
        for (int ks = 0; ks < 2; ++ks) {
            bf8 kf = *(const bf8*)(Kh + (ct * 16 + c) * 64 + ks * 32 + quad * 8);
            S[ct] = __builtin_amdgcn_mfma_f32_16x16x32_bf16(qc[ks], kf, S[ct], 0, 0, 0);
        }

    // position band R[17 tiles][4]: (Q+rpb) @ rel_k[r0 .. r0+271]^T
    const int r0 = 240 - i0w;
    f4 R[17];
#pragma unroll
    for (int rt = 0; rt < 17; ++rt) R[rt] = (f4){0.f, 0.f, 0.f, 0.f};
#pragma unroll
    for (int rt = 0; rt < 17; ++rt)
#pragma unroll
        for (int ks = 0; ks < 2; ++ks) {
            bf8 rf = *(const bf8*)(RK + (long)(r0 + rt * 16 + c) * 768 + h * 64 + ks * 32 + quad * 8);
            R[rt] = __builtin_amdgcn_mfma_f32_16x16x32_bf16(qp[ks], rf, R[rt], 0, 0, 0);
        }

    // combine: logits = S*0.125 + R[i'][15 + j - i']  via in-quad lane rotation
#pragma unroll
    for (int ct = 0; ct < 16; ++ct)
#pragma unroll
        for (int r = 0; r < 4; ++r) {
            int ip = quad * 4 + r;
            int src = (lane & 48) | ((15 - ip + c) & 15);
            float vA = __shfl(R[ct][r], src);
            float vB = __shfl(R[ct + 1][r], src);
            float pos = (c <= ip) ? vA : vB;
            S[ct][r] = S[ct][r] * 0.125f + pos;
        }

    // softmax over the 256 columns (rows live in (quad, reg); cols across 16 lanes x 16 tiles)
    float mx[4] = {-3.4e38f, -3.4e38f, -3.4e38f, -3.4e38f};
#pragma unroll
    for (int ct = 0; ct < 16; ++ct)
#pragma unroll
        for (int r = 0; r < 4; ++r) mx[r] = fmaxf(mx[r], S[ct][r]);
#pragma unroll
    for (int r = 0; r < 4; ++r)
#pragma unroll
        for (int o = 1; o < 16; o <<= 1) mx[r] = fmaxf(mx[r], __shfl_xor(mx[r], o));
    float sm[4] = {0.f, 0.f, 0.f, 0.f};
#pragma unroll
    for (int ct = 0; ct < 16; ++ct)
#pragma unroll
        for (int r = 0; r < 4; ++r) {
            float p = __expf(S[ct][r] - mx[r]);
            S[ct][r] = p;
            sm[r] += p;
        }
#pragma unroll
    for (int r = 0; r < 4; ++r)
#pragma unroll
        for (int o = 1; o < 16; o <<= 1) sm[r] += __shfl_xor(sm[r], o);
    float inv[4];
#pragma unroll
    for (int r = 0; r < 4; ++r) inv[r] = 1.0f / sm[r];

    // probs -> LDS (A-operand relayout)
#pragma unroll
    for (int ct = 0; ct < 16; ++ct)
#pragma unroll
        for (int r = 0; r < 4; ++r)
            Ps[wave][(quad * 4 + r) * 264 + ct * 16 + c] = f2bf(S[ct][r] * inv[r]);
    __syncthreads();

    // O = P @ V  (16 x 64)
    f4 O[4];
#pragma unroll
    for (int vt = 0; vt < 4; ++vt) O[vt] = (f4){0.f, 0.f, 0.f, 0.f};
#pragma unroll
    for (int kt = 0; kt < 8; ++kt) {
        bf8 af = *(const bf8*)(&Ps[wave][c * 264 + kt * 32 + quad * 8]);
#pragma unroll
        for (int vt = 0; vt < 4; ++vt) {
            bf8 bv = *(const bf8*)(&Vs[(vt * 16 + c) * 264 + kt * 32 + quad * 8]);
            O[vt] = __builtin_amdgcn_mfma_f32_16x16x32_bf16(af, bv, O[vt], 0, 0, 0);
        }
    }
    // store O in place over this wave's own q rows ((b,h,n,d) layout)
#pragma unroll
    for (int vt = 0; vt < 4; ++vt)
#pragma unroll
        for (int r = 0; r < 4; ++r)
            Qh[(i0w + quad * 4 + r) * 64 + vt * 16 + c] = f2bf(O[vt][r]);
}

// ---------------------------------------------------------------------------
extern "C" void kernel_launch(void* const* d_in, const int* in_sizes, int n_in,
                              void* d_out, int out_size, void* d_ws, size_t ws_size,
                              hipStream_t stream) {
    const float* x     = (const float*)d_in[0];   // (16384, 768)
    const float* w_qkv = (const float*)d_in[1];   // (768, 2304)
    const float* w_out = (const float*)d_in[2];   // (768, 768)
    const float* b_out = (const float*)d_in[3];   // (768,)
    const float* w_rel = (const float*)d_in[4];   // (768, 768)
    const float* rcb   = (const float*)d_in[5];   // (768,)
    const float* rpb   = (const float*)d_in[6];   // (768,)

    // ws layout (77,070,336 bytes), all internal buffers bf16
    char* ws = (char*)d_ws;
    const long QKV_BYTES = 2L * 12 * 8192 * 64 * 2;   // 25,165,824 each
    short* pos  = (short*)(ws);                        // (512, 768)  786,432 B
    short* relk = (short*)(ws + 786432L);              // (512, 768)  786,432 B
    short* q    = (short*)(ws + 1572864L);
    short* k    = (short*)(ws + 1572864L + QKV_BYTES);
    short* v    = (short*)(ws + 1572864L + 2 * QKV_BYTES);

    pos_kernel<<<512, 128, 0, stream>>>(pos);
    // rel_k = positions @ w_rel   (512 x 768), A bf16 row-major, C bf16
    gemm_k<<<dim3(4, 6), 256, 0, stream>>>(pos, w_rel, 512, 768, 768, 0,
                                           relk, nullptr, nullptr, nullptr, nullptr, nullptr);
    // qkv = x @ w_qkv (A fp32), de-interleaved into q/k/v (B,H,N,D) bf16
    gemm_k<<<dim3(128, 18), 256, 0, stream>>>(x, w_qkv, 16384, 2304, 768, 1,
                                              nullptr, nullptr, nullptr, q, k, v);
    // fused windowed attention; output overwrites q in place
    attn_k<<<6144, 128, 0, stream>>>(q, k, v, relk, rcb, rpb);
    // out = attn_out @ w_out + b_out  (A bf16 gather, C fp32 + fp32 bias)
    gemm_k<<<dim3(128, 6), 256, 0, stream>>>(q, w_out, 16384, 768, 768, 2,
                                             nullptr, (float*)d_out, b_out, nullptr, nullptr, nullptr);
}

// Round 5
// 497.250 us; speedup vs baseline: 1.8666x; 1.8666x over previous
//
#include <hip/hip_runtime.h>
#include <math.h>

typedef __attribute__((ext_vector_type(8))) short bf8;
typedef __attribute__((ext_vector_type(4))) float f4;
typedef __attribute__((ext_vector_type(2))) unsigned u2;
typedef __attribute__((ext_vector_type(4))) unsigned u4;

__device__ __forceinline__ float bf2f(short s) {
    union { unsigned u; float f; } v; v.u = ((unsigned)(unsigned short)s) << 16; return v.f;
}
// round-half-up bf16 (differs from RTNE only on exact ties)
__device__ __forceinline__ short f2bf(float f) {
    return (short)((__float_as_uint(f) + 0x8000u) >> 16);
}
// pack two fp32 -> bf16x2 (lo=a, hi=b): 2 adds + 1 v_perm
__device__ __forceinline__ unsigned pk2(float a, float b) {
    unsigned ua = __float_as_uint(a) + 0x8000u;
    unsigned ub = __float_as_uint(b) + 0x8000u;
    return __builtin_amdgcn_perm(ub, ua, 0x07060302u);
}

// ---------------------------------------------------------------------------
// Positional embedding: pos[512][768] bf16 (row 511 zero pad).
// ---------------------------------------------------------------------------
__global__ void pos_kernel(short* __restrict__ P) {
    const int row = blockIdx.x;      // 0..511
    const int j = threadIdx.x;       // 0..127  (nb = 128)
    if (row == 511) {
        for (int t = j; t < 768; t += 128) P[511 * 768 + t] = 0;
        return;
    }
    const double dist = (double)(row - 255);
    const double ad = fabs(dist);
    double hl = exp2(3.0 + 5.0 * (double)j / 127.0);
    double fe = exp(-M_LN2 / hl * ad);
    double cw = exp2((double)(j + 1)) - 1.0;
    double fc = (cw > ad) ? 1.0 : 0.0;
    double m = 2.0 + 2.0 * (double)j;
    double conc = m * m;
    double lun = (ad == 0.0) ? -INFINITY : (conc - 1.0) * log(ad);
    lun -= m * ad;
    double lnorm = lgamma(conc) - conc * log(m);
    double prob = exp(lun - lnorm) + 1e-8;
    __shared__ double red[128];
    red[j] = prob;
    __syncthreads();
    for (int s2 = 64; s2 > 0; s2 >>= 1) {
        if (j < s2) red[j] = fmax(red[j], red[j + s2]);
        __syncthreads();
    }
    double fg = prob / red[0];
    float sg = (dist > 0.0) ? 1.f : ((dist < 0.0) ? -1.f : 0.f);
    int base = row * 768;
    P[base + j]        = f2bf((float)fe);
    P[base + 128 + j]  = f2bf((float)fc);
    P[base + 256 + j]  = f2bf((float)fg);
    P[base + 384 + j]  = f2bf(sg * (float)fe);
    P[base + 512 + j]  = f2bf(sg * (float)fc);
    P[base + 640 + j]  = f2bf(sg * (float)fg);
}

// ---------------------------------------------------------------------------
// Weight transpose+convert: WT[n][k] (bf16) = W[k][n] (fp32). K,N mult of 4.
// ---------------------------------------------------------------------------
__global__ void wT_k(const float* __restrict__ W, short* __restrict__ WT,
                     int K, int N) {
    int idx = blockIdx.x * 256 + threadIdx.x;          // over N * K/4
    int kq = K >> 2;
    if (idx >= N * kq) return;
    int n = idx / kq, k = (idx % kq) << 2;
    float a = W[(long)(k + 0) * N + n];
    float b = W[(long)(k + 1) * N + n];
    float c = W[(long)(k + 2) * N + n];
    float d = W[(long)(k + 3) * N + n];
    u2 r; r.x = pk2(a, b); r.y = pk2(c, d);
    *(u2*)(WT + (long)n * K + k) = r;
}

// ---------------------------------------------------------------------------
// MFMA GEMM: C(MxN) = A(MxK) @ BT(NxK)^T, bf16 MFMA, fp32 accum.
// 128x128 tile, 4 waves, BK=32, LDS pitch 40 (conflict-free).
// mode 0: A bf16 row-major;             C -> bf16 (Cb)
// mode 1: A fp32 row-major (Af);        C -> q/k/vT de-interleave scatter
//         vT layout: (b,h,window,d,j) = ((b*12+h)*32+w)*16384 + d*256 + j
// mode 2: A bf16 gather from (b,h,n,d); C -> fp32 + fp32 bias (Cf)
// ---------------------------------------------------------------------------
__global__ __launch_bounds__(256) void gemm_k(
    const short* __restrict__ A, const float* __restrict__ Af,
    const short* __restrict__ BT,
    int M, int N, int K, int mode,
    short* __restrict__ Cb, float* __restrict__ Cf, const float* __restrict__ bias,
    short* __restrict__ Qo, short* __restrict__ Ko, short* __restrict__ Vt)
{
    __shared__ __attribute__((aligned(16))) short As[128 * 40];
    __shared__ __attribute__((aligned(16))) short Bs[128 * 40];
    const int tid = threadIdx.x;
    const int lane = tid & 63;
    const int wave = tid >> 6;
    const int wm = wave >> 1, wn = wave & 1;
    const int c = lane & 15, quad = lane >> 4;
    const int m0 = blockIdx.x * 128, n0 = blockIdx.y * 128;

    f4 acc[4][4];
#pragma unroll
    for (int i = 0; i < 4; ++i)
#pragma unroll
        for (int jx = 0; jx < 4; ++jx) acc[i][jx] = (f4){0.f, 0.f, 0.f, 0.f};

    for (int k0 = 0; k0 < K; k0 += 32) {
        // ---- stage A (128 rows x 32 k) ----
        if (mode == 1) {
#pragma unroll
            for (int i = 0; i < 2; ++i) {
                int idx = tid + i * 256;
                int row = idx >> 2, ch = (idx & 3) << 3;
                const float* src = Af + (long)(m0 + row) * K + k0 + ch;
                float4 v0 = *(const float4*)(src);
                float4 v1 = *(const float4*)(src + 4);
                u4 p; p.x = pk2(v0.x, v0.y); p.y = pk2(v0.z, v0.w);
                p.z = pk2(v1.x, v1.y); p.w = pk2(v1.z, v1.w);
                *(u4*)(&As[row * 40 + ch]) = p;
            }
        } else if (mode == 2) {
#pragma unroll
            for (int i = 0; i < 2; ++i) {
                int idx = tid + i * 256;
                int row = idx >> 2, ch = (idx & 3) << 3;
                int m = m0 + row, kk = k0 + ch;
                long off = ((long)((m >> 13) * 12 + (kk >> 6)) * 8192 + (m & 8191)) * 64 + (kk & 63);
                *(bf8*)(&As[row * 40 + ch]) = *(const bf8*)(A + off);
            }
        } else {
#pragma unroll
            for (int i = 0; i < 2; ++i) {
                int idx = tid + i * 256;
                int row = idx >> 2, ch = (idx & 3) << 3;
                *(bf8*)(&As[row * 40 + ch]) = *(const bf8*)(A + (long)(m0 + row) * K + k0 + ch);
            }
        }
        // ---- stage BT (128 n-rows x 32 k) ----
#pragma unroll
        for (int i = 0; i < 2; ++i) {
            int idx = tid + i * 256;
            int row = idx >> 2, ch = (idx & 3) << 3;
            *(bf8*)(&Bs[row * 40 + ch]) = *(const bf8*)(BT + (long)(n0 + row) * K + k0 + ch);
        }
        __syncthreads();
        bf8 a[4], b[4];
#pragma unroll
        for (int mt = 0; mt < 4; ++mt)
            a[mt] = *(const bf8*)(&As[(wm * 64 + mt * 16 + c) * 40 + quad * 8]);
#pragma unroll
        for (int nt = 0; nt < 4; ++nt)
            b[nt] = *(const bf8*)(&Bs[(wn * 64 + nt * 16 + c) * 40 + quad * 8]);
#pragma unroll
        for (int mt = 0; mt < 4; ++mt)
#pragma unroll
            for (int nt = 0; nt < 4; ++nt)
                acc[mt][nt] = __builtin_amdgcn_mfma_f32_16x16x32_bf16(a[mt], b[nt], acc[mt][nt], 0, 0, 0);
        __syncthreads();
    }
#pragma unroll
    for (int mt = 0; mt < 4; ++mt)
#pragma unroll
        for (int nt = 0; nt < 4; ++nt)
#pragma unroll
            for (int r = 0; r < 4; ++r) {
                int m = m0 + wm * 64 + mt * 16 + quad * 4 + r;
                int n = n0 + wn * 64 + nt * 16 + c;
                float val = acc[mt][nt][r];
                if (mode == 1) {
                    int sel = n % 3, hd = n / 3;        // col = (h*64+d)*3 + sel
                    int h = hd >> 6, d = hd & 63;
                    int bb = m >> 13, nn = m & 8191;
                    if (sel == 2) {                     // V transposed: (b,h,w,d,j)
                        long off = ((long)((bb * 12 + h) * 32 + (nn >> 8))) * 16384 + d * 256 + (nn & 255);
                        Vt[off] = f2bf(val);
                    } else {
                        long off = ((long)((bb * 12 + h) * 8192 + nn)) * 64 + d;
                        ((sel == 0) ? Qo : Ko)[off] = f2bf(val);
                    }
                } else if (mode == 2) {
                    Cf[(long)m * N + n] = val + bias[n];
                } else {
                    Cb[(long)m * N + n] = f2bf(val);
                }
            }
}

// ---------------------------------------------------------------------------
// Fused windowed attention. 1 block = 1 wave = 16 query rows.
// K-frags and Vt-frags read straight from global (L1/L2 resident).
// Output written in place over this wave's own q rows.
// LDS: Ps only (16x264 shorts = 8448 B), wave-private -> no barriers.
// ---------------------------------------------------------------------------
__global__ __launch_bounds__(64) void attn_k(
    short* __restrict__ Q, const short* __restrict__ Kk, const short* __restrict__ Vt,
    const short* __restrict__ RK,   // (512,768) bf16, row 511 zero; col = h*64+d
    const float* __restrict__ rcb, const float* __restrict__ rpb)
{
    __shared__ __attribute__((aligned(16))) short Ps[16 * 264];
    const int bid = blockIdx.x;
    const int s = bid & 15, w = (bid >> 4) & 31;
    const int rest = bid >> 9;
    const int h = rest % 12, b = rest / 12;
    const int lane = threadIdx.x & 63;
    const int c = lane & 15, quad = lane >> 4;
    const int i0w = s * 16;

    const long base_bh = ((long)(b * 12 + h) * 8192 + (long)w * 256) * 64;
    short* Qh = Q + base_bh;
    const short* Kh = Kk + base_bh;
    const short* Vw = Vt + (((long)(b * 12 + h) * 32 + w) << 14);   // 64x256 [d][j]

    // Q fragments with content / position biases added (bf16)
    bf8 qc[2], qp[2];
#pragma unroll
    for (int ks = 0; ks < 2; ++ks) {
        bf8 qraw = *(const bf8*)(Qh + (i0w + c) * 64 + ks * 32 + quad * 8);
        float4 cb0 = *(const float4*)(rcb + h * 64 + ks * 32 + quad * 8);
        float4 cb1 = *(const float4*)(rcb + h * 64 + ks * 32 + quad * 8 + 4);
        float4 pb0 = *(const float4*)(rpb + h * 64 + ks * 32 + quad * 8);
        float4 pb1 = *(const float4*)(rpb + h * 64 + ks * 32 + quad * 8 + 4);
        float cbv[8] = {cb0.x, cb0.y, cb0.z, cb0.w, cb1.x, cb1.y, cb1.z, cb1.w};
        float pbv[8] = {pb0.x, pb0.y, pb0.z, pb0.w, pb1.x, pb1.y, pb1.z, pb1.w};
#pragma unroll
        for (int u = 0; u < 8; ++u) {
            float qv = bf2f(qraw[u]);
            qc[ks][u] = f2bf(qv + cbv[u]);
            qp[ks][u] = f2bf(qv + pbv[u]);
        }
    }

    // content scores S[16 tiles][4]: (Q+rcb) @ K^T  (16 x 256)
    f4 S[16];
#pragma unroll
    for (int ct = 0; ct < 16; ++ct) S[ct] = (f4){0.f, 0.f, 0.f, 0.f};
#pragma unroll
    for (int ct = 0; ct < 16; ++ct)
#pragma unroll
        for (int ks = 0; ks < 2; ++ks) {
            bf8 kf = *(const bf8*)(Kh + (ct * 16 + c) * 64 + ks * 32 + quad * 8);
            S[ct] = __builtin_amdgcn_mfma_f32_16x16x32_bf16(qc[ks], kf, S[ct], 0, 0, 0);
        }

    // position band R[17 tiles][4]: (Q+rpb) @ rel_k[r0 .. r0+271]^T
    const int r0 = 240 - i0w;
    f4 R[17];
#pragma unroll
    for (int rt = 0; rt < 17; ++rt) R[rt] = (f4){0.f, 0.f, 0.f, 0.f};
#pragma unroll
    for (int rt = 0; rt < 17; ++rt)
#pragma unroll
        for (int ks = 0; ks < 2; ++ks) {
            bf8 rf = *(const bf8*)(RK + (long)(r0 + rt * 16 + c) * 768 + h * 64 + ks * 32 + quad * 8);
            R[rt] = __builtin_amdgcn_mfma_f32_16x16x32_bf16(qp[ks], rf, R[rt], 0, 0, 0);
        }

    // combine: logits = S*0.125 + R[i'][15 + j - i']  via in-quad lane rotation
#pragma unroll
    for (int ct = 0; ct < 16; ++ct)
#pragma unroll
        for (int r = 0; r < 4; ++r) {
            int ip = quad * 4 + r;
            int src = (lane & 48) | ((15 - ip + c) & 15);
            float vA = __shfl(R[ct][r], src);
            float vB = __shfl(R[ct + 1][r], src);
            float pos = (c <= ip) ? vA : vB;
            S[ct][r] = S[ct][r] * 0.125f + pos;
        }

    // softmax over the 256 columns
    float mx[4] = {-3.4e38f, -3.4e38f, -3.4e38f, -3.4e38f};
#pragma unroll
    for (int ct = 0; ct < 16; ++ct)
#pragma unroll
        for (int r = 0; r < 4; ++r) mx[r] = fmaxf(mx[r], S[ct][r]);
#pragma unroll
    for (int r = 0; r < 4; ++r)
#pragma unroll
        for (int o = 1; o < 16; o <<= 1) mx[r] = fmaxf(mx[r], __shfl_xor(mx[r], o));
    float sm[4] = {0.f, 0.f, 0.f, 0.f};
#pragma unroll
    for (int ct = 0; ct < 16; ++ct)
#pragma unroll
        for (int r = 0; r < 4; ++r) {
            float p = __expf(S[ct][r] - mx[r]);
            S[ct][r] = p;
            sm[r] += p;
        }
#pragma unroll
    for (int r = 0; r < 4; ++r)
#pragma unroll
        for (int o = 1; o < 16; o <<= 1) sm[r] += __shfl_xor(sm[r], o);
    float inv[4];
#pragma unroll
    for (int r = 0; r < 4; ++r) inv[r] = 1.0f / sm[r];

    // probs -> LDS (A-operand relayout); wave-private, no barrier needed
#pragma unroll
    for (int ct = 0; ct < 16; ++ct)
#pragma unroll
        for (int r = 0; r < 4; ++r)
            Ps[(quad * 4 + r) * 264 + ct * 16 + c] = f2bf(S[ct][r] * inv[r]);

    // O = P @ V  (16 x 64); B-frags straight from global Vt [d][j]
    f4 O[4];
#pragma unroll
    for (int vt = 0; vt < 4; ++vt) O[vt] = (f4){0.f, 0.f, 0.f, 0.f};
#pragma unroll
    for (int kt = 0; kt < 8; ++kt) {
        bf8 af = *(const bf8*)(&Ps[c * 264 + kt * 32 + quad * 8]);
#pragma unroll
        for (int vt = 0; vt < 4; ++vt) {
            bf8 bv = *(const bf8*)(Vw + (vt * 16 + c) * 256 + kt * 32 + quad * 8);
            O[vt] = __builtin_amdgcn_mfma_f32_16x16x32_bf16(af, bv, O[vt], 0, 0, 0);
        }
    }
    // store O in place over this wave's own q rows ((b,h,n,d) layout)
#pragma unroll
    for (int vt = 0; vt < 4; ++vt)
#pragma unroll
        for (int r = 0; r < 4; ++r)
            Qh[(i0w + quad * 4 + r) * 64 + vt * 16 + c] = f2bf(O[vt][r]);
}

// ---------------------------------------------------------------------------
extern "C" void kernel_launch(void* const* d_in, const int* in_sizes, int n_in,
                              void* d_out, int out_size, void* d_ws, size_t ws_size,
                              hipStream_t stream) {
    const float* x     = (const float*)d_in[0];   // (16384, 768)
    const float* w_qkv = (const float*)d_in[1];   // (768, 2304)
    const float* w_out = (const float*)d_in[2];   // (768, 768)
    const float* b_out = (const float*)d_in[3];   // (768,)
    const float* w_rel = (const float*)d_in[4];   // (768, 768)
    const float* rcb   = (const float*)d_in[5];   // (768,)
    const float* rpb   = (const float*)d_in[6];   // (768,)

    // ws layout (~83.0 MB), all internal buffers bf16
    char* ws = (char*)d_ws;
    short* wqkvT = (short*)(ws);                       // (2304,768)  3,538,944 B
    short* woutT = (short*)(ws + 3538944L);            // (768,768)   1,179,648 B
    short* wrelT = (short*)(ws + 4718592L);            // (768,768)   1,179,648 B
    short* pos   = (short*)(ws + 5898240L);            // (512,768)     786,432 B
    short* relk  = (short*)(ws + 6684672L);            // (512,768)     786,432 B
    short* q     = (short*)(ws + 7471104L);            // 25,165,824 B
    short* k     = (short*)(ws + 32636928L);
    short* vT    = (short*)(ws + 57802752L);

    // weight transpose+convert (fp32 -> bf16 [n][k])
    wT_k<<<(2304 * 192 + 255) / 256, 256, 0, stream>>>(w_qkv, wqkvT, 768, 2304);
    wT_k<<<(768 * 192 + 255) / 256, 256, 0, stream>>>(w_out, woutT, 768, 768);
    wT_k<<<(768 * 192 + 255) / 256, 256, 0, stream>>>(w_rel, wrelT, 768, 768);
    pos_kernel<<<512, 128, 0, stream>>>(pos);
    // rel_k = positions @ w_rel   (512 x 768)
    gemm_k<<<dim3(4, 6), 256, 0, stream>>>(pos, nullptr, wrelT, 512, 768, 768, 0,
                                           relk, nullptr, nullptr, nullptr, nullptr, nullptr);
    // qkv = x @ w_qkv, de-interleaved into q/k (b,h,n,d) and vT (b,h,w,d,j)
    gemm_k<<<dim3(128, 18), 256, 0, stream>>>(nullptr, x, wqkvT, 16384, 2304, 768, 1,
                                              nullptr, nullptr, nullptr, q, k, vT);
    // fused windowed attention; output overwrites q in place
    attn_k<<<12288, 64, 0, stream>>>(q, k, vT, relk, rcb, rpb);
    // out = attn_out @ w_out + b_out
    gemm_k<<<dim3(128, 6), 256, 0, stream>>>(q, nullptr, woutT, 16384, 768, 768, 2,
                                             nullptr, (float*)d_out, b_out, nullptr, nullptr, nullptr);
}

// Round 6
// 465.829 us; speedup vs baseline: 1.9925x; 1.0675x over previous
//
#include <hip/hip_runtime.h>
#include <math.h>

typedef __attribute__((ext_vector_type(8))) short bf8;
typedef __attribute__((ext_vector_type(4))) float f4;
typedef __attribute__((ext_vector_type(2))) unsigned u2;
typedef __attribute__((ext_vector_type(4))) unsigned u4;

__device__ __forceinline__ float bf2f(short s) {
    union { unsigned u; float f; } v; v.u = ((unsigned)(unsigned short)s) << 16; return v.f;
}
// round-half-up bf16 (differs from RTNE only on exact ties)
__device__ __forceinline__ short f2bf(float f) {
    return (short)((__float_as_uint(f) + 0x8000u) >> 16);
}
// pack two fp32 -> bf16x2 (lo=a, hi=b): 2 adds + 1 v_perm
__device__ __forceinline__ unsigned pk2(float a, float b) {
    unsigned ua = __float_as_uint(a) + 0x8000u;
    unsigned ub = __float_as_uint(b) + 0x8000u;
    return __builtin_amdgcn_perm(ub, ua, 0x07060302u);
}

// ---------------------------------------------------------------------------
// Positional embedding: pos[512][768] bf16 (row 511 zero pad).
// ---------------------------------------------------------------------------
__global__ void pos_kernel(short* __restrict__ P) {
    const int row = blockIdx.x;      // 0..511
    const int j = threadIdx.x;       // 0..127  (nb = 128)
    if (row == 511) {
        for (int t = j; t < 768; t += 128) P[511 * 768 + t] = 0;
        return;
    }
    const double dist = (double)(row - 255);
    const double ad = fabs(dist);
    double hl = exp2(3.0 + 5.0 * (double)j / 127.0);
    double fe = exp(-M_LN2 / hl * ad);
    double cw = exp2((double)(j + 1)) - 1.0;
    double fc = (cw > ad) ? 1.0 : 0.0;
    double m = 2.0 + 2.0 * (double)j;
    double conc = m * m;
    double lun = (ad == 0.0) ? -INFINITY : (conc - 1.0) * log(ad);
    lun -= m * ad;
    double lnorm = lgamma(conc) - conc * log(m);
    double prob = exp(lun - lnorm) + 1e-8;
    __shared__ double red[128];
    red[j] = prob;
    __syncthreads();
    for (int s2 = 64; s2 > 0; s2 >>= 1) {
        if (j < s2) red[j] = fmax(red[j], red[j + s2]);
        __syncthreads();
    }
    double fg = prob / red[0];
    float sg = (dist > 0.0) ? 1.f : ((dist < 0.0) ? -1.f : 0.f);
    int base = row * 768;
    P[base + j]        = f2bf((float)fe);
    P[base + 128 + j]  = f2bf((float)fc);
    P[base + 256 + j]  = f2bf((float)fg);
    P[base + 384 + j]  = f2bf(sg * (float)fe);
    P[base + 512 + j]  = f2bf(sg * (float)fc);
    P[base + 640 + j]  = f2bf(sg * (float)fg);
}

// ---------------------------------------------------------------------------
// Weight transpose+convert: WT[n][k] (bf16) = W[k][n] (fp32). K,N mult of 4.
// ---------------------------------------------------------------------------
__global__ void wT_k(const float* __restrict__ W, short* __restrict__ WT,
                     int K, int N) {
    int idx = blockIdx.x * 256 + threadIdx.x;          // over N * K/4
    int kq = K >> 2;
    if (idx >= N * kq) return;
    int n = idx / kq, k = (idx % kq) << 2;
    float a = W[(long)(k + 0) * N + n];
    float b = W[(long)(k + 1) * N + n];
    float c = W[(long)(k + 2) * N + n];
    float d = W[(long)(k + 3) * N + n];
    u2 r; r.x = pk2(a, b); r.y = pk2(c, d);
    *(u2*)(WT + (long)n * K + k) = r;
}

// ---------------------------------------------------------------------------
// MFMA GEMM: C(MxN) = A(MxK) @ BT(NxK)^T, bf16 MFMA, fp32 accum.
// 128x128 tile, 4 waves, BK=32, LDS pitch 40 (conflict-free).
// mode 0: A bf16 row-major;             C -> bf16 (Cb)
// mode 1: A fp32 row-major (Af);        C -> q/k/vT de-interleave scatter
//         vT layout: (b,h,window,d,j) = ((b*12+h)*32+w)*16384 + d*256 + j
// mode 2: A bf16 gather from (b,h,n,d); C -> fp32 + fp32 bias (Cf)
// ---------------------------------------------------------------------------
__global__ __launch_bounds__(256) void gemm_k(
    const short* __restrict__ A, const float* __restrict__ Af,
    const short* __restrict__ BT,
    int M, int N, int K, int mode,
    short* __restrict__ Cb, float* __restrict__ Cf, const float* __restrict__ bias,
    short* __restrict__ Qo, short* __restrict__ Ko, short* __restrict__ Vt)
{
    __shared__ __attribute__((aligned(16))) short As[128 * 40];
    __shared__ __attribute__((aligned(16))) short Bs[128 * 40];
    const int tid = threadIdx.x;
    const int lane = tid & 63;
    const int wave = tid >> 6;
    const int wm = wave >> 1, wn = wave & 1;
    const int c = lane & 15, quad = lane >> 4;
    const int m0 = blockIdx.x * 128, n0 = blockIdx.y * 128;

    f4 acc[4][4];
#pragma unroll
    for (int i = 0; i < 4; ++i)
#pragma unroll
        for (int jx = 0; jx < 4; ++jx) acc[i][jx] = (f4){0.f, 0.f, 0.f, 0.f};

    for (int k0 = 0; k0 < K; k0 += 32) {
        // ---- stage A (128 rows x 32 k) ----
        if (mode == 1) {
#pragma unroll
            for (int i = 0; i < 2; ++i) {
                int idx = tid + i * 256;
                int row = idx >> 2, ch = (idx & 3) << 3;
                const float* src = Af + (long)(m0 + row) * K + k0 + ch;
                float4 v0 = *(const float4*)(src);
                float4 v1 = *(const float4*)(src + 4);
                u4 p; p.x = pk2(v0.x, v0.y); p.y = pk2(v0.z, v0.w);
                p.z = pk2(v1.x, v1.y); p.w = pk2(v1.z, v1.w);
                *(u4*)(&As[row * 40 + ch]) = p;
            }
        } else if (mode == 2) {
#pragma unroll
            for (int i = 0; i < 2; ++i) {
                int idx = tid + i * 256;
                int row = idx >> 2, ch = (idx & 3) << 3;
                int m = m0 + row, kk = k0 + ch;
                long off = ((long)((m >> 13) * 12 + (kk >> 6)) * 8192 + (m & 8191)) * 64 + (kk & 63);
                *(bf8*)(&As[row * 40 + ch]) = *(const bf8*)(A + off);
            }
        } else {
#pragma unroll
            for (int i = 0; i < 2; ++i) {
                int idx = tid + i * 256;
                int row = idx >> 2, ch = (idx & 3) << 3;
                *(bf8*)(&As[row * 40 + ch]) = *(const bf8*)(A + (long)(m0 + row) * K + k0 + ch);
            }
        }
        // ---- stage BT (128 n-rows x 32 k) ----
#pragma unroll
        for (int i = 0; i < 2; ++i) {
            int idx = tid + i * 256;
            int row = idx >> 2, ch = (idx & 3) << 3;
            *(bf8*)(&Bs[row * 40 + ch]) = *(const bf8*)(BT + (long)(n0 + row) * K + k0 + ch);
        }
        __syncthreads();
        bf8 a[4], b[4];
#pragma unroll
        for (int mt = 0; mt < 4; ++mt)
            a[mt] = *(const bf8*)(&As[(wm * 64 + mt * 16 + c) * 40 + quad * 8]);
#pragma unroll
        for (int nt = 0; nt < 4; ++nt)
            b[nt] = *(const bf8*)(&Bs[(wn * 64 + nt * 16 + c) * 40 + quad * 8]);
#pragma unroll
        for (int mt = 0; mt < 4; ++mt)
#pragma unroll
            for (int nt = 0; nt < 4; ++nt)
                acc[mt][nt] = __builtin_amdgcn_mfma_f32_16x16x32_bf16(a[mt], b[nt], acc[mt][nt], 0, 0, 0);
        __syncthreads();
    }
#pragma unroll
    for (int mt = 0; mt < 4; ++mt)
#pragma unroll
        for (int nt = 0; nt < 4; ++nt)
#pragma unroll
            for (int r = 0; r < 4; ++r) {
                int m = m0 + wm * 64 + mt * 16 + quad * 4 + r;
                int n = n0 + wn * 64 + nt * 16 + c;
                float val = acc[mt][nt][r];
                if (mode == 1) {
                    int sel = n % 3, hd = n / 3;        // col = (h*64+d)*3 + sel
                    int h = hd >> 6, d = hd & 63;
                    int bb = m >> 13, nn = m & 8191;
                    if (sel == 2) {                     // V transposed: (b,h,w,d,j)
                        long off = ((long)((bb * 12 + h) * 32 + (nn >> 8))) * 16384 + d * 256 + (nn & 255);
                        Vt[off] = f2bf(val);
                    } else {
                        long off = ((long)((bb * 12 + h) * 8192 + nn)) * 64 + d;
                        ((sel == 0) ? Qo : Ko)[off] = f2bf(val);
                    }
                } else if (mode == 2) {
                    Cf[(long)m * N + n] = val + bias[n];
                } else {
                    Cb[(long)m * N + n] = f2bf(val);
                }
            }
}

// ---------------------------------------------------------------------------
// Fused windowed attention v2. 1 block = 4 waves = 64 q-rows; 4 blocks/window.
// Phase 1: K window staged to LDS (pitch 72), S = (Q+rcb)K^T from LDS.
// R band from global (rel_k is 0.8 MB, L2-hot).
// Phase 2: same LDS buffer re-staged with Vt [d][j] (pitch 264); PV in two
// j-halves so Ps is 16x136 per wave (wave-private, no barriers for Ps).
// LDS: 36864 (Ks/Vs) + 17408 (Ps) = 54272 B -> 3 blocks/CU.
// Output written in place over each wave's own 16 q rows.
// ---------------------------------------------------------------------------
__global__ __launch_bounds__(256) void attn_k(
    short* __restrict__ Q, const short* __restrict__ Kk, const short* __restrict__ Vt,
    const short* __restrict__ RK,   // (512,768) bf16, row 511 zero; col = h*64+d
    const float* __restrict__ rcb, const float* __restrict__ rpb)
{
    __shared__ __attribute__((aligned(16))) short Ks[256 * 72];    // then Vs[64][264]
    __shared__ __attribute__((aligned(16))) short Ps[4][16 * 136];
    const int bid = blockIdx.x;
    const int strip = bid & 3, w = (bid >> 2) & 31;
    const int rest = bid >> 7;
    const int h = rest % 12, b = rest / 12;
    const int tid = threadIdx.x, lane = tid & 63, wave = tid >> 6;
    const int c = lane & 15, quad = lane >> 4;
    const int i0w = strip * 64 + wave * 16;

    const long base_bh = ((long)(b * 12 + h) * 8192 + (long)w * 256) * 64;
    short* Qh = Q + base_bh;
    const short* Kh = Kk + base_bh;
    const short* Vw = Vt + (((long)(b * 12 + h) * 32 + w) << 14);   // 64x256 [d][j]

    // stage K window [j][d] into LDS, pitch 72
#pragma unroll
    for (int i = 0; i < 8; ++i) {
        int p = tid + i * 256;
        int row = p >> 3, ch = (p & 7) << 3;
        *(bf8*)(&Ks[row * 72 + ch]) = *(const bf8*)(Kh + row * 64 + ch);
    }

    // Q fragments with content / position biases added (bf16)
    bf8 qc[2], qp[2];
#pragma unroll
    for (int ks = 0; ks < 2; ++ks) {
        bf8 qraw = *(const bf8*)(Qh + (i0w + c) * 64 + ks * 32 + quad * 8);
        float4 cb0 = *(const float4*)(rcb + h * 64 + ks * 32 + quad * 8);
        float4 cb1 = *(const float4*)(rcb + h * 64 + ks * 32 + quad * 8 + 4);
        float4 pb0 = *(const float4*)(rpb + h * 64 + ks * 32 + quad * 8);
        float4 pb1 = *(const float4*)(rpb + h * 64 + ks * 32 + quad * 8 + 4);
        float cbv[8] = {cb0.x, cb0.y, cb0.z, cb0.w, cb1.x, cb1.y, cb1.z, cb1.w};
        float pbv[8] = {pb0.x, pb0.y, pb0.z, pb0.w, pb1.x, pb1.y, pb1.z, pb1.w};
#pragma unroll
        for (int u = 0; u < 8; ++u) {
            float qv = bf2f(qraw[u]);
            qc[ks][u] = f2bf(qv + cbv[u]);
            qp[ks][u] = f2bf(qv + pbv[u]);
        }
    }
    __syncthreads();   // Ks ready

    // content scores S[16 tiles][4]: (Q+rcb) @ K^T from LDS  (16 x 256)
    f4 S[16];
#pragma unroll
    for (int ct = 0; ct < 16; ++ct) S[ct] = (f4){0.f, 0.f, 0.f, 0.f};
#pragma unroll
    for (int ct = 0; ct < 16; ++ct)
#pragma unroll
        for (int ks = 0; ks < 2; ++ks) {
            bf8 kf = *(const bf8*)(&Ks[(ct * 16 + c) * 72 + ks * 32 + quad * 8]);
            S[ct] = __builtin_amdgcn_mfma_f32_16x16x32_bf16(qc[ks], kf, S[ct], 0, 0, 0);
        }

    // position band R[17 tiles][4]: (Q+rpb) @ rel_k[r0 .. r0+271]^T (global)
    const int r0 = 240 - i0w;
    f4 R[17];
#pragma unroll
    for (int rt = 0; rt < 17; ++rt) R[rt] = (f4){0.f, 0.f, 0.f, 0.f};
#pragma unroll
    for (int rt = 0; rt < 17; ++rt)
#pragma unroll
        for (int ks = 0; ks < 2; ++ks) {
            bf8 rf = *(const bf8*)(RK + (long)(r0 + rt * 16 + c) * 768 + h * 64 + ks * 32 + quad * 8);
            R[rt] = __builtin_amdgcn_mfma_f32_16x16x32_bf16(qp[ks], rf, R[rt], 0, 0, 0);
        }
    __syncthreads();   // all waves done reading Ks

    // re-stage same LDS with Vt window [d][j], pitch 264
    short* Vs = Ks;
#pragma unroll
    for (int i = 0; i < 8; ++i) {
        int p = tid + i * 256;
        int row = p >> 5, ch = (p & 31) << 3;
        *(bf8*)(&Vs[row * 264 + ch]) = *(const bf8*)(Vw + row * 256 + ch);
    }

    // combine: logits = S*0.125 + R[i'][15 + j - i']  via in-quad lane rotation
#pragma unroll
    for (int ct = 0; ct < 16; ++ct)
#pragma unroll
        for (int r = 0; r < 4; ++r) {
            int ip = quad * 4 + r;
            int src = (lane & 48) | ((15 - ip + c) & 15);
            float vA = __shfl(R[ct][r], src);
            float vB = __shfl(R[ct + 1][r], src);
            float pos = (c <= ip) ? vA : vB;
            S[ct][r] = S[ct][r] * 0.125f + pos;
        }

    // softmax over the 256 columns
    float mx[4] = {-3.4e38f, -3.4e38f, -3.4e38f, -3.4e38f};
#pragma unroll
    for (int ct = 0; ct < 16; ++ct)
#pragma unroll
        for (int r = 0; r < 4; ++r) mx[r] = fmaxf(mx[r], S[ct][r]);
#pragma unroll
    for (int r = 0; r < 4; ++r)
#pragma unroll
        for (int o = 1; o < 16; o <<= 1) mx[r] = fmaxf(mx[r], __shfl_xor(mx[r], o));
    float sm[4] = {0.f, 0.f, 0.f, 0.f};
#pragma unroll
    for (int ct = 0; ct < 16; ++ct)
#pragma unroll
        for (int r = 0; r < 4; ++r) {
            float p = __expf(S[ct][r] - mx[r]);
            S[ct][r] = p;
            sm[r] += p;
        }
#pragma unroll
    for (int r = 0; r < 4; ++r)
#pragma unroll
        for (int o = 1; o < 16; o <<= 1) sm[r] += __shfl_xor(sm[r], o);
    float inv[4];
#pragma unroll
    for (int r = 0; r < 4; ++r) inv[r] = 1.0f / sm[r];

    __syncthreads();   // Vs ready

    // O = P @ V in two j-halves; Ps wave-private (DS ops in-order per wave)
    f4 O[4];
#pragma unroll
    for (int vt = 0; vt < 4; ++vt) O[vt] = (f4){0.f, 0.f, 0.f, 0.f};
#pragma unroll
    for (int half = 0; half < 2; ++half) {
#pragma unroll
        for (int ct = 0; ct < 8; ++ct)
#pragma unroll
            for (int r = 0; r < 4; ++r)
                Ps[wave][(quad * 4 + r) * 136 + ct * 16 + c] = f2bf(S[half * 8 + ct][r] * inv[r]);
#pragma unroll
        for (int kt = 0; kt < 4; ++kt) {
            bf8 af = *(const bf8*)(&Ps[wave][c * 136 + kt * 32 + quad * 8]);
#pragma unroll
            for (int vt = 0; vt < 4; ++vt) {
                bf8 bv = *(const bf8*)(&Vs[(vt * 16 + c) * 264 + (half * 4 + kt) * 32 + quad * 8]);
                O[vt] = __builtin_amdgcn_mfma_f32_16x16x32_bf16(af, bv, O[vt], 0, 0, 0);
            }
        }
    }
    // store O in place over this wave's own q rows ((b,h,n,d) layout)
#pragma unroll
    for (int vt = 0; vt < 4; ++vt)
#pragma unroll
        for (int r = 0; r < 4; ++r)
            Qh[(i0w + quad * 4 + r) * 64 + vt * 16 + c] = f2bf(O[vt][r]);
}

// ---------------------------------------------------------------------------
extern "C" void kernel_launch(void* const* d_in, const int* in_sizes, int n_in,
                              void* d_out, int out_size, void* d_ws, size_t ws_size,
                              hipStream_t stream) {
    const float* x     = (const float*)d_in[0];   // (16384, 768)
    const float* w_qkv = (const float*)d_in[1];   // (768, 2304)
    const float* w_out = (const float*)d_in[2];   // (768, 768)
    const float* b_out = (const float*)d_in[3];   // (768,)
    const float* w_rel = (const float*)d_in[4];   // (768, 768)
    const float* rcb   = (const float*)d_in[5];   // (768,)
    const float* rpb   = (const float*)d_in[6];   // (768,)

    // ws layout (~83.0 MB), all internal buffers bf16
    char* ws = (char*)d_ws;
    short* wqkvT = (short*)(ws);                       // (2304,768)  3,538,944 B
    short* woutT = (short*)(ws + 3538944L);            // (768,768)   1,179,648 B
    short* wrelT = (short*)(ws + 4718592L);            // (768,768)   1,179,648 B
    short* pos   = (short*)(ws + 5898240L);            // (512,768)     786,432 B
    short* relk  = (short*)(ws + 6684672L);            // (512,768)     786,432 B
    short* q     = (short*)(ws + 7471104L);            // 25,165,824 B
    short* k     = (short*)(ws + 32636928L);
    short* vT    = (short*)(ws + 57802752L);

    // weight transpose+convert (fp32 -> bf16 [n][k])
    wT_k<<<(2304 * 192 + 255) / 256, 256, 0, stream>>>(w_qkv, wqkvT, 768, 2304);
    wT_k<<<(768 * 192 + 255) / 256, 256, 0, stream>>>(w_out, woutT, 768, 768);
    wT_k<<<(768 * 192 + 255) / 256, 256, 0, stream>>>(w_rel, wrelT, 768, 768);
    pos_kernel<<<512, 128, 0, stream>>>(pos);
    // rel_k = positions @ w_rel   (512 x 768)
    gemm_k<<<dim3(4, 6), 256, 0, stream>>>(pos, nullptr, wrelT, 512, 768, 768, 0,
                                           relk, nullptr, nullptr, nullptr, nullptr, nullptr);
    // qkv = x @ w_qkv, de-interleaved into q/k (b,h,n,d) and vT (b,h,w,d,j)
    gemm_k<<<dim3(128, 18), 256, 0, stream>>>(nullptr, x, wqkvT, 16384, 2304, 768, 1,
                                              nullptr, nullptr, nullptr, q, k, vT);
    // fused windowed attention; output overwrites q in place
    attn_k<<<3072, 256, 0, stream>>>(q, k, vT, relk, rcb, rpb);
    // out = attn_out @ w_out + b_out
    gemm_k<<<dim3(128, 6), 256, 0, stream>>>(q, nullptr, woutT, 16384, 768, 768, 2,
                                             nullptr, (float*)d_out, b_out, nullptr, nullptr, nullptr);
}